// Round 7
// baseline (152.433 us; speedup 1.0000x reference)
//
#include <hip/hip_runtime.h>

// Problem constants (GATLayer): B=4, N=2048, TOKEN_DIM=512, HIDDEN=128
// v13: ALGORITHMIC REWRITE of attention via leaky-softmax separability.
//   p_ij = exp(leaky(ci+sj)) = (z>=0) ? exp(ci)exp(sj) : exp(.01ci)exp(.01sj),
//   branch decided by sj >= -ci  (threshold on sj alone). So with j value-
//   sorted (counting sort into 1024 value bins; within-bin order irrelevant
//   at bin granularity; boundary-bin error <= binwidth ~ 0.008 in p-units,
//   ~4e-5 on out, and exactly 0 at z=0 by continuity):
//     out_i = [e1i*SS1[r_i] + e2i*PS2[r_i]] / [e1i*ss1[r_i] + e2i*ps2[r_i]]
//   where SS1[r]=suffix sums of exp(sj)h_j, PS2[r]=prefix sums of
//   exp(.01sj)h_j in sorted order, r_i = binStart[bin(-ci)+1].
// Dispatches: k_prep (fc_w->bf16), k_fused (FC+LN+scores, h fp32),
//   k_sortscan (per-batch bin/counting-sort), k_scan (build tables),
//   k_out (lookup + scale). PV-MFMA, 16.7M exps, bf16 P/h all eliminated.
#define NB      4
#define NTOK    2048
#define TOKDIM  512
#define HID     128
#define NROWS   (NB * NTOK)      // 8192
#define LN_EPS  1e-5f
#define NEG_SLOPE 0.01f
#define NBIN    1024
#define TBSTR   (2049 * 128)     // table batch stride (floats)

typedef short bf16x8 __attribute__((ext_vector_type(8)));   // 8 bf16 in 4 VGPRs
typedef float f32x4  __attribute__((ext_vector_type(4)));

static __device__ __forceinline__ unsigned short f2bf(float f) {
    union { float f; unsigned int i; } v; v.f = f;
    unsigned int i = v.i;
    i += 0x7FFFu + ((i >> 16) & 1u);   // round-to-nearest-even
    return (unsigned short)(i >> 16);
}

// ---------------------------------------------------------------------------
// k_prep: convert fc_w (128x512 fp32) -> bf16 once. 64 blocks x 256 thr.
// ---------------------------------------------------------------------------
__global__ __launch_bounds__(256) void k_prep(const float* __restrict__ W,
                                              unsigned short* __restrict__ Wb) {
    const int g = blockIdx.x * 256 + threadIdx.x;   // 0..16383
    float4 v = *(const float4*)(W + (size_t)g * 4);
    ushort4 o;
    o.x = f2bf(v.x); o.y = f2bf(v.y); o.z = f2bf(v.z); o.w = f2bf(v.w);
    *(ushort4*)(Wb + (size_t)g * 4) = o;
}

// ---------------------------------------------------------------------------
// k_fused (v9 core, validated): FC(MFMA)+bias+LN+scores. 256 blocks x 1024.
// Change vs v9: h written FP32 row-major (no bf16, no transpose, no phase E).
// ---------------------------------------------------------------------------
__global__ __launch_bounds__(1024) void k_fused(const float* __restrict__ X,
                                                const unsigned short* __restrict__ Wb,
                                                const float* __restrict__ fcb,
                                                const float* __restrict__ attnw,
                                                const float* __restrict__ attnb,
                                                const float* __restrict__ lng,
                                                const float* __restrict__ lnb,
                                                float* __restrict__ hOut,
                                                float* __restrict__ srow,
                                                float* __restrict__ cc) {
    __shared__ char smem[33280 + 32 * 132 * 4];      // 50176 B
    unsigned short* ldsX = (unsigned short*)smem;    // [32][520]
    float* hfull = (float*)(smem + 33280);           // [32][132]

    const int tid   = threadIdx.x;
    const int wv    = tid >> 6;
    const int lane  = tid & 63;
    const int m     = lane & 15;
    const int q     = lane >> 4;
    const int rowbase = blockIdx.x * 32;
    const int nbase   = (wv & 7) * 16;
    const int rhalf   = (wv >> 3) * 16;              // 0 or 16

    // ---- phase A: stage X tile (32 rows) -> LDS bf16
    {
        const int r  = tid >> 5;            // 0..31
        const int c0 = (tid & 31) * 16;     // 0..496
        const float* xp = X + (size_t)(rowbase + r) * TOKDIM + c0;
        bf16x8 v0, v1;
#pragma unroll
        for (int u = 0; u < 8; ++u) v0[u] = (short)f2bf(xp[u]);
#pragma unroll
        for (int u = 0; u < 8; ++u) v1[u] = (short)f2bf(xp[8 + u]);
        *(bf16x8*)&ldsX[r * 520 + c0]     = v0;
        *(bf16x8*)&ldsX[r * 520 + c0 + 8] = v1;
    }
    __syncthreads();

    // ---- phase B: MFMA. A[m][k] from ldsX (row-half offset), B from bf16 Wb.
    const unsigned short* wp = Wb + (size_t)(nbase + m) * TOKDIM + q * 8;
    f32x4 acc = {0.f, 0.f, 0.f, 0.f};
#pragma unroll
    for (int kk = 0; kk < TOKDIM / 32; ++kk) {
        bf16x8 a = *(const bf16x8*)&ldsX[(rhalf + m) * 520 + kk * 32 + q * 8];
        bf16x8 b = *(const bf16x8*)(wp + kk * 32);
        acc = __builtin_amdgcn_mfma_f32_16x16x32_bf16(a, b, acc, 0, 0, 0);
    }

    // ---- phase C: acc (+fc_b) -> hfull LDS  (validated C/D mapping)
    {
        const float bias = fcb[nbase + m];
#pragma unroll
        for (int r = 0; r < 4; ++r)
            hfull[(rhalf + q * 4 + r) * 132 + nbase + m] = acc[r] + bias;
    }
    __syncthreads();

    // ---- phase D: LN + scores; h written FP32 to global
    {
        const int r   = tid >> 5;           // row 0..31
        const int l32 = tid & 31;
        const int c0  = l32 * 4;
        float4 hv = *(const float4*)&hfull[r * 132 + c0];
        float v[4] = {hv.x, hv.y, hv.z, hv.w};

        float s  = v[0] + v[1] + v[2] + v[3];
        float ss = v[0]*v[0] + v[1]*v[1] + v[2]*v[2] + v[3]*v[3];
#pragma unroll
        for (int d = 1; d < 32; d <<= 1) {
            s  += __shfl_xor(s,  d, 64);
            ss += __shfl_xor(ss, d, 64);
        }
        float mu  = s * (1.f / HID);
        float var = ss * (1.f / HID) - mu * mu;
        float rs  = rsqrtf(var + LN_EPS);

        float n0[4], sr = 0.f, sc = 0.f;
#pragma unroll
        for (int k = 0; k < 4; ++k) {
            n0[k] = lng[c0 + k] * (v[k] - mu) * rs + lnb[c0 + k];
            sr += n0[k] * attnw[c0 + k];
            sc += n0[k] * attnw[HID + c0 + k];
        }
        float4 ho = {n0[0], n0[1], n0[2], n0[3]};
        *(float4*)&hOut[(size_t)(rowbase + r) * HID + c0] = ho;
#pragma unroll
        for (int d = 1; d < 32; d <<= 1) {
            sr += __shfl_xor(sr, d, 64);
            sc += __shfl_xor(sc, d, 64);
        }
        if (l32 == 0) {
            int grow = rowbase + r;
            srow[grow] = sr;
            cc[grow]   = sc + attnb[0];
        }
    }
}

// ---------------------------------------------------------------------------
// k_sortscan: per batch (4 blocks x 1024 thr): min/max, 1024-bin histogram,
// prefix -> binStart, counting-sort scatter of (idx, exp(s), exp(.01s)).
// Within-bin order is irrelevant (tables are consumed at bin granularity).
// ---------------------------------------------------------------------------
__global__ __launch_bounds__(1024) void k_sortscan(const float* __restrict__ srow,
                                                   int* __restrict__ sIdx,
                                                   float* __restrict__ E1s,
                                                   float* __restrict__ E2s,
                                                   int* __restrict__ binStart,
                                                   float2* __restrict__ loscale) {
    __shared__ int   hist[NBIN];
    __shared__ int   cur[NBIN];
    __shared__ int   bst[NBIN];
    __shared__ int   chunkOff[32];
    __shared__ float wmin[16], wmax[16];
    __shared__ float sLo, sSc;

    const int b   = blockIdx.x;
    const int tid = threadIdx.x;
    const float v0 = srow[b * NTOK + tid];
    const float v1 = srow[b * NTOK + 1024 + tid];
    hist[tid] = 0;

    float mn = fminf(v0, v1), mx = fmaxf(v0, v1);
#pragma unroll
    for (int d = 1; d < 64; d <<= 1) {
        mn = fminf(mn, __shfl_xor(mn, d, 64));
        mx = fmaxf(mx, __shfl_xor(mx, d, 64));
    }
    if ((tid & 63) == 0) { wmin[tid >> 6] = mn; wmax[tid >> 6] = mx; }
    __syncthreads();
    if (tid == 0) {
        float lo = wmin[0], hi = wmax[0];
        for (int k = 1; k < 16; ++k) { lo = fminf(lo, wmin[k]); hi = fmaxf(hi, wmax[k]); }
        float range = fmaxf(hi - lo, 1e-6f);
        sLo = lo; sSc = (float)(NBIN - 1) / range;
        float2 ls; ls.x = lo; ls.y = sSc;
        loscale[b] = ls;
    }
    __syncthreads();
    const float lo = sLo, scl = sSc;
    int b0 = (int)((v0 - lo) * scl); b0 = b0 < 0 ? 0 : (b0 > NBIN - 1 ? NBIN - 1 : b0);
    int b1 = (int)((v1 - lo) * scl); b1 = b1 < 0 ? 0 : (b1 > NBIN - 1 ? NBIN - 1 : b1);
    atomicAdd(&hist[b0], 1);
    atomicAdd(&hist[b1], 1);
    __syncthreads();

    // exclusive prefix of hist -> bst (two-level)
    if (tid < 32) {
        int s = 0;
        for (int m2 = 0; m2 < 32; ++m2) s += hist[tid * 32 + m2];
        chunkOff[tid] = s;
    }
    __syncthreads();
    if (tid == 0) {
        int run = 0;
        for (int c = 0; c < 32; ++c) { int t = chunkOff[c]; chunkOff[c] = run; run += t; }
    }
    __syncthreads();
    {
        int base = tid & ~31;
        int off = chunkOff[tid >> 5];
        for (int m2 = base; m2 < tid; ++m2) off += hist[m2];
        bst[tid] = off;
        cur[tid] = off;
    }
    __syncthreads();

    // scatter
    {
        int slot = atomicAdd(&cur[b0], 1);
        sIdx[b * NTOK + slot] = tid;
        E1s[b * NTOK + slot] = __expf(v0);
        E2s[b * NTOK + slot] = __expf(NEG_SLOPE * v0);
    }
    {
        int slot = atomicAdd(&cur[b1], 1);
        sIdx[b * NTOK + slot] = 1024 + tid;
        E1s[b * NTOK + slot] = __expf(v1);
        E2s[b * NTOK + slot] = __expf(NEG_SLOPE * v1);
    }
    binStart[b * (NBIN + 1) + tid] = bst[tid];
    if (tid == 0) binStart[b * (NBIN + 1) + NBIN] = NTOK;
}

// ---------------------------------------------------------------------------
// k_scan: build SS1 (suffix of exp(s)h) / PS2 (prefix of exp(.01s)h) tables.
// Blocks 0..31: (b=bid>>3, seg=bid&7), 512 thr = (d 0..127, q 0..3).
//   Phase A: thread walks quarter q at 64-granularity -> part[32][128] LDS.
//   Offsets (q==0 threads): off2 = ascending-exclusive, off1 = descending-
//   exclusive. Phase B: thread emits its global sub = seg*4+q (64 rows).
// Blocks 32..35: scalar tables ss1s/ps2s per batch (32 working threads).
// ---------------------------------------------------------------------------
__global__ __launch_bounds__(512) void k_scan(const float* __restrict__ h,
                                              const int* __restrict__ sIdx,
                                              const float* __restrict__ E1s,
                                              const float* __restrict__ E2s,
                                              float* __restrict__ SS1,
                                              float* __restrict__ PS2,
                                              float* __restrict__ ss1s,
                                              float* __restrict__ ps2s) {
    __shared__ float part1[32][128], part2[32][128];
    __shared__ float off1[32][128], off2[32][128];
    __shared__ float sp1[32], sp2[32];

    const int bid = blockIdx.x;
    const int tid = threadIdx.x;

    if (bid < 32) {
        const int b = bid >> 3, seg = bid & 7;
        const int d = tid & 127, q = tid >> 7;
        const int*   si = sIdx + b * NTOK;
        const float* e1 = E1s + b * NTOK;
        const float* e2 = E2s + b * NTOK;
        const float* hb = h + (size_t)b * NTOK * HID;

        // phase A: 64-granularity partials for the whole batch (quarter q)
        for (int sub = q * 8; sub < q * 8 + 8; ++sub) {
            float a1 = 0.f, a2 = 0.f;
            for (int kk = 0; kk < 64; ++kk) {
                int k = sub * 64 + kk;
                float hv = hb[(size_t)si[k] * HID + d];
                a1 += e1[k] * hv;
                a2 += e2[k] * hv;
            }
            part1[sub][d] = a1;
            part2[sub][d] = a2;
        }
        __syncthreads();
        if (q == 0) {
            float r2 = 0.f;
            for (int s = 0; s < 32; ++s) { off2[s][d] = r2; r2 += part2[s][d]; }
            float r1 = 0.f;
            for (int s = 31; s >= 0; --s) { off1[s][d] = r1; r1 += part1[s][d]; }
        }
        __syncthreads();

        // phase B: emit sub = seg*4 + q
        const int sub = seg * 4 + q;
        float* S = SS1 + (size_t)b * TBSTR;
        float* P = PS2 + (size_t)b * TBSTR;
        float run2 = off2[sub][d];
        for (int kk = 0; kk < 64; ++kk) {
            int k = sub * 64 + kk;
            float hv = hb[(size_t)si[k] * HID + d];
            P[(size_t)k * HID + d] = run2;
            run2 += e2[k] * hv;
        }
        if (sub == 31) {
            P[(size_t)NTOK * HID + d] = run2;
            S[(size_t)NTOK * HID + d] = 0.f;
        }
        float run1 = off1[sub][d];
        for (int kk = 63; kk >= 0; --kk) {
            int k = sub * 64 + kk;
            float hv = hb[(size_t)si[k] * HID + d];
            run1 += e1[k] * hv;
            S[(size_t)k * HID + d] = run1;
        }
    } else {
        const int b = bid - 32;
        const float* e1 = E1s + b * NTOK;
        const float* e2 = E2s + b * NTOK;
        if (tid < 32) {
            float a1 = 0.f, a2 = 0.f;
            for (int kk = 0; kk < 64; ++kk) { a1 += e1[tid * 64 + kk]; a2 += e2[tid * 64 + kk]; }
            sp1[tid] = a1; sp2[tid] = a2;
        }
        __syncthreads();
        if (tid < 32) {
            float o2 = 0.f; for (int s = 0; s < tid; ++s)      o2 += sp2[s];
            float o1 = 0.f; for (int s = tid + 1; s < 32; ++s) o1 += sp1[s];
            float* pb = ps2s + b * 2049;
            float* sb = ss1s + b * 2049;
            float run2 = o2;
            for (int kk = 0; kk < 64; ++kk) { int k = tid * 64 + kk; pb[k] = run2; run2 += e2[k]; }
            if (tid == 31) { pb[NTOK] = run2; sb[NTOK] = 0.f; }
            float run1 = o1;
            for (int kk = 63; kk >= 0; --kk) { int k = tid * 64 + kk; run1 += e1[k]; sb[k] = run1; }
        }
    }
}

// ---------------------------------------------------------------------------
// k_out: 128 blocks x 512 thr; block = 64 rows of one batch. Per row: O(1)
// bin lookup -> r, then out = (e1i*SS1[r] + e2i*PS2[r]) / (e1i*ss1 + e2i*ps2).
// ---------------------------------------------------------------------------
__global__ __launch_bounds__(512) void k_out(const float* __restrict__ cc,
                                             const int* __restrict__ binStart,
                                             const float2* __restrict__ loscale,
                                             const float* __restrict__ SS1,
                                             const float* __restrict__ PS2,
                                             const float* __restrict__ ss1s,
                                             const float* __restrict__ ps2s,
                                             float* __restrict__ out) {
    const int bid = blockIdx.x;
    const int b = bid >> 5, rb = bid & 31;
    const int tid = threadIdx.x;
    const int rl = tid >> 3, oct = tid & 7;
    const int grow = b * NTOK + rb * 64 + rl;

    const float ci  = cc[grow];
    const float2 ls = loscale[b];
    const float e1i = __expf(ci);
    const float e2i = __expf(NEG_SLOPE * ci);
    const float fi  = (-ci - ls.x) * ls.y;
    int r;
    if (fi < 0.f)             r = 0;
    else if (fi >= (float)NBIN) r = NTOK;
    else                      r = binStart[b * (NBIN + 1) + (int)fi + 1];

    const float den  = e1i * ss1s[b * 2049 + r] + e2i * ps2s[b * 2049 + r];
    const float rden = 1.f / den;
    const float* S = SS1 + (size_t)b * TBSTR + (size_t)r * HID + oct * 16;
    const float* P = PS2 + (size_t)b * TBSTR + (size_t)r * HID + oct * 16;
    float* o = out + (size_t)grow * HID + oct * 16;
#pragma unroll
    for (int g = 0; g < 4; ++g) {
        float4 sv = *(const float4*)(S + g * 4);
        float4 pv = *(const float4*)(P + g * 4);
        float4 ov;
        ov.x = (e1i * sv.x + e2i * pv.x) * rden;
        ov.y = (e1i * sv.y + e2i * pv.y) * rden;
        ov.z = (e1i * sv.z + e2i * pv.z) * rden;
        ov.w = (e1i * sv.w + e2i * pv.w) * rden;
        *(float4*)(o + g * 4) = ov;
    }
}

// ---------------------------------------------------------------------------
extern "C" void kernel_launch(void* const* d_in, const int* in_sizes, int n_in,
                              void* d_out, int out_size, void* d_ws, size_t ws_size,
                              hipStream_t stream) {
    const float* X     = (const float*)d_in[0]; // token_embedding [4,2048,512]
    const float* W     = (const float*)d_in[1]; // fc_w [128,512]
    const float* fcb   = (const float*)d_in[2]; // fc_b [128]
    const float* attnw = (const float*)d_in[3]; // attn_w [1,256]
    const float* attnb = (const float*)d_in[4]; // attn_b [1]
    const float* lng   = (const float*)d_in[5]; // ln_g [128]
    const float* lnb   = (const float*)d_in[6]; // ln_b [128]
    float* out = (float*)d_out;                 // h_prime [4,2048,128] fp32

    char* ws = (char*)d_ws;
    float*          hO   = (float*)(ws);                          // 4 MB
    float*          srow = (float*)(ws + 4194304);                // 32 KB
    float*          cchd = (float*)(ws + 4194304 + 32768);        // 32 KB
    unsigned short* Wb   = (unsigned short*)(ws + 4194304 + 65536);   // 128 KB
    int*            sIdx = (int*)(ws + 4194304 + 196608);         // 32 KB
    float*          E1s  = (float*)(ws + 4194304 + 229376);       // 32 KB
    float*          E2s  = (float*)(ws + 4194304 + 262144);       // 32 KB
    int*            binS = (int*)(ws + 4194304 + 294912);         // 16.4 KB
    float2*         losc = (float2*)(ws + 4194304 + 327680);      // 32 B
    float*          SS1  = (float*)(ws + 8388608);                // 4.2 MB
    float*          PS2  = (float*)(ws + 12582912);               // 4.2 MB
    float*          ss1s = (float*)(ws + 17825792);               // 32.8 KB
    float*          ps2s = (float*)(ws + 17825792 + 65536);       // 32.8 KB

    k_prep    <<<64, 256, 0, stream>>>(W, Wb);
    k_fused   <<<NROWS / 32, 1024, 0, stream>>>(X, Wb, fcb, attnw, attnb, lng, lnb,
                                                hO, srow, cchd);
    k_sortscan<<<NB, 1024, 0, stream>>>(srow, sIdx, E1s, E2s, binS, losc);
    k_scan    <<<36, 512, 0, stream>>>(hO, sIdx, E1s, E2s, SS1, PS2, ss1s, ps2s);
    k_out     <<<128, 512, 0, stream>>>(cchd, binS, losc, SS1, PS2, ss1s, ps2s, out);
}

// Round 8
// 106.258 us; speedup vs baseline: 1.4346x; 1.4346x over previous
//
#include <hip/hip_runtime.h>

// Problem constants (GATLayer): B=4, N=2048, TOKEN_DIM=512, HIDDEN=128
// IO dtype: fp32. Internally: bf16 MFMA with fp32 accumulate.
// v14 == v9 (best measured: 104.9 us). Reverted after v10-v13 experiments
// (intra-wave interleave, k-split, wave specialization, sort/scan algorithmic
// rewrite) all measured slower. Three dispatches:
//   k_prep : fc_w fp32 -> bf16 (RTNE) once into workspace.
//   k_fused: 32-row blocks x 1024 thr (16 waves; twin waves share Wb slices
//            via L1 -> halves Wb L2 traffic vs 16-row blocks).
//   k_attn : produce-ahead software pipeline -- produce(ch+1) sits in the
//            same barrier region as consume(ch).
// All fp32->bf16 via manual RTNE f2bf (validated in passing runs).
#define NB      4
#define NTOK    2048
#define TOKDIM  512
#define HID     128
#define NROWS   (NB * NTOK)      // 8192
#define LN_EPS  1e-5f
#define NEG_SLOPE 0.01f

typedef short bf16x8 __attribute__((ext_vector_type(8)));   // 8 bf16 in 4 VGPRs
typedef float f32x4  __attribute__((ext_vector_type(4)));

static __device__ __forceinline__ unsigned short f2bf(float f) {
    union { float f; unsigned int i; } v; v.f = f;
    unsigned int i = v.i;
    i += 0x7FFFu + ((i >> 16) & 1u);   // round-to-nearest-even
    return (unsigned short)(i >> 16);
}

// ---------------------------------------------------------------------------
// k_prep: convert fc_w (128x512 fp32) -> bf16 once. 64 blocks x 256 thr.
// ---------------------------------------------------------------------------
__global__ __launch_bounds__(256) void k_prep(const float* __restrict__ W,
                                              unsigned short* __restrict__ Wb) {
    const int g = blockIdx.x * 256 + threadIdx.x;   // 0..16383
    float4 v = *(const float4*)(W + (size_t)g * 4);
    ushort4 o;
    o.x = f2bf(v.x); o.y = f2bf(v.y); o.z = f2bf(v.z); o.w = f2bf(v.w);
    *(ushort4*)(Wb + (size_t)g * 4) = o;
}

// ---------------------------------------------------------------------------
// k_fused (v9): per 32-row tile: FC (MFMA, A from LDS-staged bf16 X, B from
// pre-converted bf16 Wb) + bias + LayerNorm + scores + transposed hT write.
// Grid 256 blocks x 1024 thr (16 waves). Wave wv: n-cols [(wv&7)*16,+16),
// row-half (wv>>3)*16. Twin waves (wv, wv+8) read identical Wb slices (L1).
// ---------------------------------------------------------------------------
__global__ __launch_bounds__(1024) void k_fused(const float* __restrict__ X,
                                                const unsigned short* __restrict__ Wb,
                                                const float* __restrict__ fcb,
                                                const float* __restrict__ attnw,
                                                const float* __restrict__ attnb,
                                                const float* __restrict__ lng,
                                                const float* __restrict__ lnb,
                                                unsigned short* __restrict__ hT,
                                                float* __restrict__ srow,
                                                float* __restrict__ cc) {
    __shared__ char smem[33280 + 32 * 132 * 4];      // 50176 B
    unsigned short* ldsX = (unsigned short*)smem;    // [32][520]
    unsigned short* ldsT = (unsigned short*)smem;    // [128][36] (reuse)
    float* hfull = (float*)(smem + 33280);           // [32][132]

    const int tid   = threadIdx.x;
    const int wv    = tid >> 6;
    const int lane  = tid & 63;
    const int m     = lane & 15;
    const int q     = lane >> 4;
    const int rowbase = blockIdx.x * 32;
    const int nbase   = (wv & 7) * 16;
    const int rhalf   = (wv >> 3) * 16;              // 0 or 16

    // ---- phase A: stage X tile (32 rows) -> LDS bf16
    {
        const int r  = tid >> 5;            // 0..31
        const int c0 = (tid & 31) * 16;     // 0..496
        const float* xp = X + (size_t)(rowbase + r) * TOKDIM + c0;
        bf16x8 v0, v1;
#pragma unroll
        for (int u = 0; u < 8; ++u) v0[u] = (short)f2bf(xp[u]);
#pragma unroll
        for (int u = 0; u < 8; ++u) v1[u] = (short)f2bf(xp[8 + u]);
        *(bf16x8*)&ldsX[r * 520 + c0]     = v0;
        *(bf16x8*)&ldsX[r * 520 + c0 + 8] = v1;
    }
    __syncthreads();

    // ---- phase B: MFMA. A[m][k] from ldsX (row-half offset), B from bf16 Wb.
    const unsigned short* wp = Wb + (size_t)(nbase + m) * TOKDIM + q * 8;
    f32x4 acc = {0.f, 0.f, 0.f, 0.f};
#pragma unroll
    for (int kk = 0; kk < TOKDIM / 32; ++kk) {
        bf16x8 a = *(const bf16x8*)&ldsX[(rhalf + m) * 520 + kk * 32 + q * 8];
        bf16x8 b = *(const bf16x8*)(wp + kk * 32);
        acc = __builtin_amdgcn_mfma_f32_16x16x32_bf16(a, b, acc, 0, 0, 0);
    }

    // ---- phase C: acc (+fc_b) -> hfull LDS  (validated C/D mapping)
    {
        const float bias = fcb[nbase + m];
#pragma unroll
        for (int r = 0; r < 4; ++r)
            hfull[(rhalf + q * 4 + r) * 132 + nbase + m] = acc[r] + bias;
    }
    __syncthreads();   // hfull ready; ldsX dead (safe to reuse as ldsT)

    // ---- phase D: LN + scores; write bf16 h into ldsT transposed
    {
        const int r   = tid >> 5;           // row 0..31
        const int l32 = tid & 31;
        const int c0  = l32 * 4;
        float4 hv = *(const float4*)&hfull[r * 132 + c0];
        float v[4] = {hv.x, hv.y, hv.z, hv.w};

        float s  = v[0] + v[1] + v[2] + v[3];
        float ss = v[0]*v[0] + v[1]*v[1] + v[2]*v[2] + v[3]*v[3];
#pragma unroll
        for (int d = 1; d < 32; d <<= 1) {
            s  += __shfl_xor(s,  d, 64);
            ss += __shfl_xor(ss, d, 64);
        }
        float mu  = s * (1.f / HID);
        float var = ss * (1.f / HID) - mu * mu;
        float rs  = rsqrtf(var + LN_EPS);

        float n[4], sr = 0.f, sc = 0.f;
#pragma unroll
        for (int k = 0; k < 4; ++k) {
            n[k] = lng[c0 + k] * (v[k] - mu) * rs + lnb[c0 + k];
            sr += n[k] * attnw[c0 + k];
            sc += n[k] * attnw[HID + c0 + k];
            ldsT[(c0 + k) * 36 + r] = f2bf(n[k]);
        }
#pragma unroll
        for (int d = 1; d < 32; d <<= 1) {
            sr += __shfl_xor(sr, d, 64);
            sc += __shfl_xor(sc, d, 64);
        }
        if (l32 == 0) {
            int grow = rowbase + r;
            srow[grow] = sr;
            cc[grow]   = sc + attnb[0];
        }
    }
    __syncthreads();

    // ---- phase E: coalesced hT write. thread t: d = t>>3, 4 j's of 32.
    {
        const int d  = tid >> 3;                   // 0..127
        const int j4 = (tid & 7) * 4;              // 0..28
        const int b    = blockIdx.x >> 6;          // 64 blocks per batch
        const int jblk = (blockIdx.x & 63) * 32;
        ushort4 o;
        o.x = ldsT[d * 36 + j4 + 0];
        o.y = ldsT[d * 36 + j4 + 1];
        o.z = ldsT[d * 36 + j4 + 2];
        o.w = ldsT[d * 36 + j4 + 3];
        *(ushort4*)(hT + ((size_t)(b * HID + d)) * NTOK + jblk + j4) = o;
    }
}

// ---------------------------------------------------------------------------
// k_attn v7 (best measured): 256 blocks x 512 thr (8 waves); block owns 32
// i-rows; j in 8 chunks of 256. produce(ch+1) is in the SAME barrier region
// as consume(ch).
//  RAW: consume(ch+1) reads pP[(ch+1)&1] after barrier(ch).     -> safe
//  WAR: produce(ch+2) writes pP[ch&1] after barrier(ch+1), and
//       consume(ch) read pP[ch&1] before barrier(ch).           -> safe
// ---------------------------------------------------------------------------
static __device__ __forceinline__ void produce_chunk(
        unsigned short* __restrict__ dst,   // &pP[buf][i_loc][jseg]
        float ci, float4 s0, float4 s1, float4 s2, float4 s3,
        float& lsum) {
    float sv[16] = {s0.x, s0.y, s0.z, s0.w, s1.x, s1.y, s1.z, s1.w,
                    s2.x, s2.y, s2.z, s2.w, s3.x, s3.y, s3.z, s3.w};
    bf16x8 v0, v1;
#pragma unroll
    for (int u = 0; u < 8; ++u) {
        float z = ci + sv[u];
        z = fmaxf(z, NEG_SLOPE * z);
        float p = __expf(z);
        lsum += p;
        v0[u] = (short)f2bf(p);
    }
#pragma unroll
    for (int u = 0; u < 8; ++u) {
        float z = ci + sv[8 + u];
        z = fmaxf(z, NEG_SLOPE * z);
        float p = __expf(z);
        lsum += p;
        v1[u] = (short)f2bf(p);
    }
    *(bf16x8*)dst       = v0;
    *(bf16x8*)(dst + 8) = v1;
}

__global__ __launch_bounds__(512) void k_attn(const unsigned short* __restrict__ hT,
                                              const float* __restrict__ srow,
                                              const float* __restrict__ cc,
                                              float* __restrict__ out) {
    __shared__ unsigned short pP[2][32][264];   // 2 x 16896 B, +8 pad
    __shared__ float pDen[32][16];              // 2 KB
    __shared__ float denv[32];

    const int tid  = threadIdx.x;
    const int wv   = tid >> 6;
    const int lane = tid & 63;
    const int m    = lane & 15;
    const int q    = lane >> 4;
    const int rowbase = blockIdx.x * 32;     // global row base
    const int b    = blockIdx.x >> 6;        // 64 blocks per batch
    const int dbase = wv * 16;

    // producer indices
    const int i_loc = tid >> 4;              // 0..31
    const int jseg  = (tid & 15) * 16;       // 0..240
    const float ci  = cc[rowbase + i_loc];
    const float* sp = srow + (size_t)b * NTOK + jseg;

    // consumer B pointer
    const unsigned short* hp =
        hT + ((size_t)(b * HID + dbase + m)) * NTOK + q * 8;

    f32x4 acc0 = {0.f, 0.f, 0.f, 0.f};      // i-subtile 0 (rows 0..15)
    f32x4 acc1 = {0.f, 0.f, 0.f, 0.f};      // i-subtile 1 (rows 16..31)
    float lsum = 0.f;

    // ---- prefetch srow(0) + B(0); produce chunk 0; prefetch srow(1)
    float4 s0 = *(const float4*)(sp);
    float4 s1 = *(const float4*)(sp + 4);
    float4 s2 = *(const float4*)(sp + 8);
    float4 s3 = *(const float4*)(sp + 12);
    bf16x8 bcur[8], bnxt[8];
#pragma unroll
    for (int s = 0; s < 8; ++s) bcur[s] = *(const bf16x8*)(hp + s * 32);

    produce_chunk(&pP[0][i_loc][jseg], ci, s0, s1, s2, s3, lsum);

    float4 n0, n1, n2, n3;
    {
        const float* spn = sp + 256;
        n0 = *(const float4*)(spn);
        n1 = *(const float4*)(spn + 4);
        n2 = *(const float4*)(spn + 8);
        n3 = *(const float4*)(spn + 12);
    }

    __syncthreads();   // pP[0] ready

#pragma unroll
    for (int ch = 0; ch < 8; ++ch) {
        if (ch < 7) {
            // ---- produce chunk ch+1 (VALU; overlaps MFMA consume below)
            produce_chunk(&pP[(ch + 1) & 1][i_loc][jseg], ci, n0, n1, n2, n3, lsum);

            // ---- prefetch srow(ch+2) for next iteration's produce
            if (ch < 6) {
                const float* spn = sp + (ch + 2) * 256;
                n0 = *(const float4*)(spn);
                n1 = *(const float4*)(spn + 4);
                n2 = *(const float4*)(spn + 8);
                n3 = *(const float4*)(spn + 12);
            }
            // ---- prefetch B(ch+1) for next iteration's consume
            const unsigned short* hpn = hp + (ch + 1) * 256;
#pragma unroll
            for (int s = 0; s < 8; ++s) bnxt[s] = *(const bf16x8*)(hpn + s * 32);
        }

        // ---- consume chunk ch: 8 k-steps, B-frag reused by both i-subtiles
#pragma unroll
        for (int s = 0; s < 8; ++s) {
            bf16x8 a0 = *(const bf16x8*)&pP[ch & 1][m][s * 32 + q * 8];
            bf16x8 a1 = *(const bf16x8*)&pP[ch & 1][16 + m][s * 32 + q * 8];
            acc0 = __builtin_amdgcn_mfma_f32_16x16x32_bf16(a0, bcur[s], acc0, 0, 0, 0);
            acc1 = __builtin_amdgcn_mfma_f32_16x16x32_bf16(a1, bcur[s], acc1, 0, 0, 0);
        }

        __syncthreads();   // pP[(ch+1)&1] complete; consume(ch) drained

#pragma unroll
        for (int s = 0; s < 8; ++s) bcur[s] = bnxt[s];
    }

    // ---- denominators: thread covered (i_loc, jseg window) across chunks
    pDen[i_loc][tid & 15] = lsum;
    __syncthreads();
    if (tid < 32) {
        float d = 0.f;
#pragma unroll
        for (int k = 0; k < 16; ++k) d += pDen[tid][k];
        denv[tid] = 1.f / d;
    }
    __syncthreads();

    // ---- epilogue: out[row=i][col=d], validated C/D mapping
#pragma unroll
    for (int r = 0; r < 4; ++r) {
        int r0 = q * 4 + r;
        out[(size_t)(rowbase + r0) * HID + dbase + m]      = acc0[r] * denv[r0];
        out[(size_t)(rowbase + 16 + r0) * HID + dbase + m] = acc1[r] * denv[16 + r0];
    }
}

// ---------------------------------------------------------------------------
extern "C" void kernel_launch(void* const* d_in, const int* in_sizes, int n_in,
                              void* d_out, int out_size, void* d_ws, size_t ws_size,
                              hipStream_t stream) {
    const float* X     = (const float*)d_in[0]; // token_embedding [4,2048,512]
    const float* W     = (const float*)d_in[1]; // fc_w [128,512]
    const float* fcb   = (const float*)d_in[2]; // fc_b [128]
    const float* attnw = (const float*)d_in[3]; // attn_w [1,256]
    const float* attnb = (const float*)d_in[4]; // attn_b [1]
    const float* lng   = (const float*)d_in[5]; // ln_g [128]
    const float* lnb   = (const float*)d_in[6]; // ln_b [128]
    float* out = (float*)d_out;                 // h_prime [4,2048,128] fp32

    char* ws = (char*)d_ws;
    unsigned short* hT   = (unsigned short*)ws;                          // 2 MB
    float*          srow = (float*)(ws + 2u * 1024 * 1024);              // 32 KB
    float*          cchd = (float*)(ws + 2u * 1024 * 1024 + 32u * 1024); // 32 KB
    unsigned short* Wb   = (unsigned short*)(ws + 2u * 1024 * 1024 + 64u * 1024); // 128 KB

    k_prep <<<64, 256, 0, stream>>>(W, Wb);
    k_fused<<<NROWS / 32, 1024, 0, stream>>>(X, Wb, fcb, attnw, attnb, lng, lnb,
                                             hT, srow, cchd);
    k_attn <<<NROWS / 32, 512, 0, stream>>>(hT, srow, cchd, out);
}